// Round 11
// baseline (12200.395 us; speedup 1.0000x reference)
//
#include <hip/hip_runtime.h>
#include <hip/hip_bf16.h>
#include <math.h>

// ---------------- problem constants ----------------
static constexpr int NB   = 64;           // batch
static constexpr int SS   = 197;          // tokens
static constexpr int DD   = 768;          // hidden
static constexpr int NHH  = 12;           // heads
static constexpr int DHH  = 64;           // head dim
static constexpr int FFF  = 3072;         // mlp hidden
static constexpr int TOK  = NB * SS;      // 12608
static constexpr int NPAT = 196;          // patches per image
static constexpr int PADM = 12672;        // TOK padded to multiple of 128
static constexpr int PADM2= 12800;        // TOK padded to multiple of 256
static constexpr long NX  = (long)TOK * DD;  // 9,682,944

typedef __attribute__((ext_vector_type(8))) short bf16x8;
typedef __attribute__((ext_vector_type(4))) float f32x4;

__device__ inline void gll16(const __hip_bfloat16* g, __hip_bfloat16* l) {
    __builtin_amdgcn_global_load_lds(
        (const __attribute__((address_space(1))) void*)g,
        (__attribute__((address_space(3))) void*)l, 16, 0, 0);
}

// =====================================================================
// 128x128 tile bf16 MFMA GEMM (3-buffer, stage-ahead-2, 1 barrier/iter)
// — unchanged from round 10. Used for mapper / proj / MLP2 (N=768).
// =====================================================================
template<int EPI, bool OUTBF>
__global__ __launch_bounds__(256, 4) void gemm128(
    const __hip_bfloat16* __restrict__ A, int lda,
    const __hip_bfloat16* __restrict__ Bt, int ldb,
    void* __restrict__ Cout, int ldc,
    const float* __restrict__ bias,
    const float* __restrict__ Rm, int ldr,
    float* __restrict__ out2,
    int M, int N, int K)
{
    __shared__ __hip_bfloat16 sh[3][2][128 * 32];   // 48 KiB

    const int nbx = gridDim.x;
    const int nwg = nbx * gridDim.y;
    int flat = blockIdx.y * nbx + blockIdx.x;
    {
        int q = nwg >> 3, r = nwg & 7;
        int xcd = flat & 7, idx = flat >> 3;
        flat = (xcd < r ? xcd * (q + 1) : r * (q + 1) + (xcd - r) * q) + idx;
    }
    const int m0 = (flat / nbx) * 128;
    const int n0 = (flat % nbx) * 128;

    const int t = threadIdx.x;
    const int wid = t >> 6, lane = t & 63;
    const int wm = wid >> 1, wn = wid & 1;
    const int l15 = lane & 15, g0 = lane >> 4;
    const int rcol = ((g0 ^ ((l15 >> 1) & 3)) * 8);

    const int srl = t >> 2, sg = t & 3;

    auto stage = [&](int buf, int k0) {
        #pragma unroll
        for (int j = 0; j < 2; ++j) {
            int row = j * 64 + srl;
            int gs = sg ^ ((row >> 1) & 3);
            gll16(A + (long)(m0 + row) * lda + k0 + gs * 8,
                  &sh[buf][0][row * 32 + sg * 8]);
        }
        #pragma unroll
        for (int j = 0; j < 2; ++j) {
            int row = j * 64 + srl;
            int gs = sg ^ ((row >> 1) & 3);
            gll16(Bt + (long)(n0 + row) * ldb + k0 + gs * 8,
                  &sh[buf][1][row * 32 + sg * 8]);
        }
    };

    f32x4 acc[4][4] = {};
    const int NT = K >> 5;

    stage(0, 0);
    stage(1, 32);
    asm volatile("s_waitcnt vmcnt(4)" ::: "memory");
    __builtin_amdgcn_sched_barrier(0);
    __builtin_amdgcn_s_barrier();
    __builtin_amdgcn_sched_barrier(0);

    int cur = 0;
    for (int kt = 0; kt < NT; ++kt) {
        const bool st2 = (kt + 2 < NT);
        const bool w1n = (kt + 1 < NT);
        int stbuf = cur + 2; if (stbuf >= 3) stbuf -= 3;

        bf16x8 af[4], bfr[4];
        #pragma unroll
        for (int mi = 0; mi < 4; ++mi)
            af[mi] = *reinterpret_cast<const bf16x8*>(
                &sh[cur][0][(wm * 64 + mi * 16 + l15) * 32 + rcol]);
        #pragma unroll
        for (int ni = 0; ni < 4; ++ni)
            bfr[ni] = *reinterpret_cast<const bf16x8*>(
                &sh[cur][1][(wn * 64 + ni * 16 + l15) * 32 + rcol]);

        if (st2) stage(stbuf, (kt + 2) << 5);

        asm volatile("s_waitcnt lgkmcnt(0)" ::: "memory");
        __builtin_amdgcn_sched_barrier(0);
        __builtin_amdgcn_s_setprio(1);
        #pragma unroll
        for (int mi = 0; mi < 4; ++mi)
            #pragma unroll
            for (int ni = 0; ni < 4; ++ni)
                acc[mi][ni] = __builtin_amdgcn_mfma_f32_16x16x32_bf16(
                    af[mi], bfr[ni], acc[mi][ni], 0, 0, 0);
        __builtin_amdgcn_s_setprio(0);
        __builtin_amdgcn_sched_barrier(0);
        if (st2)      { asm volatile("s_waitcnt vmcnt(4)" ::: "memory"); }
        else if (w1n) { asm volatile("s_waitcnt vmcnt(0)" ::: "memory"); }
        __builtin_amdgcn_sched_barrier(0);
        __builtin_amdgcn_s_barrier();
        __builtin_amdgcn_sched_barrier(0);

        cur = (cur == 2) ? 0 : cur + 1;
    }

    #pragma unroll
    for (int mi = 0; mi < 4; ++mi) {
        #pragma unroll
        for (int r = 0; r < 4; ++r) {
            int gm = m0 + wm * 64 + mi * 16 + (lane >> 4) * 4 + r;
            if (gm >= M) continue;
            #pragma unroll
            for (int ni = 0; ni < 4; ++ni) {
                int gn = n0 + wn * 64 + ni * 16 + (lane & 15);
                float v = acc[mi][ni][r];
                if (bias) v += bias[gn];
                if (EPI == 1) v += Rm[(long)gm * ldr + gn];
                if (EPI == 2) v = 0.5f * v * (1.0f + erff(v * 0.70710678118654752f));
                if (OUTBF) {
                    ((__hip_bfloat16*)Cout)[(long)gm * ldc + gn] = __float2bfloat16(v);
                } else {
                    ((float*)Cout)[(long)gm * ldc + gn] = v;
                    if (EPI == 1 && out2) out2[(long)gm * ldc + gn] = v;
                }
            }
        }
    }
}

// =====================================================================
// 256x128 tile bf16 MFMA GEMM, BK=32, 8 waves (4Mx2N, wave-tile 64x64),
// double-buffered LDS (48 KiB), stage-ahead-2 into current buffer,
// counted vmcnt(3), XOR bank-swizzle, setprio, XCD-swizzled grid.
// Higher arithmetic intensity (24 KB staged per 2.1 MFLOP) than 128².
// Used for MLP1 (N=3072). Requires N mult 128, K mult 32 (>=64),
// A rows readable to next multiple of 256.
// =====================================================================
template<int EPI, bool OUTBF>
__global__ __launch_bounds__(512, 6) void gemm256(
    const __hip_bfloat16* __restrict__ A, int lda,
    const __hip_bfloat16* __restrict__ Bt, int ldb,
    void* __restrict__ Cout, int ldc,
    const float* __restrict__ bias,
    const float* __restrict__ Rm, int ldr,
    float* __restrict__ out2,
    int M, int N, int K)
{
    __shared__ __hip_bfloat16 sh[2][(256 + 128) * 32];   // 48 KiB; A then B

    const int nbx = gridDim.x;
    const int nwg = nbx * gridDim.y;
    int flat = blockIdx.y * nbx + blockIdx.x;
    {
        int q = nwg >> 3, r = nwg & 7;
        int xcd = flat & 7, idx = flat >> 3;
        flat = (xcd < r ? xcd * (q + 1) : r * (q + 1) + (xcd - r) * q) + idx;
    }
    const int m0 = (flat / nbx) * 256;
    const int n0 = (flat % nbx) * 128;

    const int t = threadIdx.x;
    const int wid = t >> 6, lane = t & 63;
    const int wm = wid >> 1, wn = wid & 1;        // 4M x 2N
    const int l15 = lane & 15, g0 = lane >> 4;
    const int rcol = ((g0 ^ ((l15 >> 1) & 3)) * 8);

    const int srl = t >> 2, sg = t & 3;           // srl 0..127

    auto stage = [&](int buf, int k0) {
        #pragma unroll
        for (int j = 0; j < 2; ++j) {             // A: rows 0..255
            int row = j * 128 + srl;
            int gs = sg ^ ((row >> 1) & 3);
            gll16(A + (long)(m0 + row) * lda + k0 + gs * 8,
                  &sh[buf][row * 32 + sg * 8]);
        }
        {                                          // B: rows 0..127
            int gs = sg ^ ((srl >> 1) & 3);
            gll16(Bt + (long)(n0 + srl) * ldb + k0 + gs * 8,
                  &sh[buf][8192 + srl * 32 + sg * 8]);
        }
    };

    f32x4 acc[4][4] = {};
    const int NT = K >> 5;

    stage(0, 0);
    stage(1, 32);
    asm volatile("s_waitcnt vmcnt(3)" ::: "memory");
    __builtin_amdgcn_sched_barrier(0);
    __builtin_amdgcn_s_barrier();
    __builtin_amdgcn_sched_barrier(0);

    for (int kt = 0; kt < NT; ++kt) {
        const int cur = kt & 1;
        const bool st2 = (kt + 2 < NT);
        const bool w1n = (kt + 1 < NT);

        // phase A: fragment reads from buf[cur]
        bf16x8 af[4], bfr[4];
        #pragma unroll
        for (int mi = 0; mi < 4; ++mi)
            af[mi] = *reinterpret_cast<const bf16x8*>(
                &sh[cur][(wm * 64 + mi * 16 + l15) * 32 + rcol]);
        #pragma unroll
        for (int ni = 0; ni < 4; ++ni)
            bfr[ni] = *reinterpret_cast<const bf16x8*>(
                &sh[cur][8192 + (wn * 64 + ni * 16 + l15) * 32 + rcol]);
        asm volatile("s_waitcnt lgkmcnt(0)" ::: "memory");
        __builtin_amdgcn_sched_barrier(0);
        __builtin_amdgcn_s_barrier();       // block-wide: buf[cur] fully read
        __builtin_amdgcn_sched_barrier(0);

        // phase B: refill buf[cur] with tile kt+2; MFMA; counted wait
        if (st2) stage(cur, (kt + 2) << 5);
        __builtin_amdgcn_s_setprio(1);
        #pragma unroll
        for (int mi = 0; mi < 4; ++mi)
            #pragma unroll
            for (int ni = 0; ni < 4; ++ni)
                acc[mi][ni] = __builtin_amdgcn_mfma_f32_16x16x32_bf16(
                    af[mi], bfr[ni], acc[mi][ni], 0, 0, 0);
        __builtin_amdgcn_s_setprio(0);
        __builtin_amdgcn_sched_barrier(0);
        if (st2)      { asm volatile("s_waitcnt vmcnt(3)" ::: "memory"); }  // kt+1 landed
        else if (w1n) { asm volatile("s_waitcnt vmcnt(0)" ::: "memory"); }  // tail drain
        __builtin_amdgcn_sched_barrier(0);
        __builtin_amdgcn_s_barrier();
        __builtin_amdgcn_sched_barrier(0);
    }

    #pragma unroll
    for (int mi = 0; mi < 4; ++mi) {
        #pragma unroll
        for (int r = 0; r < 4; ++r) {
            int gm = m0 + wm * 64 + mi * 16 + (lane >> 4) * 4 + r;
            if (gm >= M) continue;
            #pragma unroll
            for (int ni = 0; ni < 4; ++ni) {
                int gn = n0 + wn * 64 + ni * 16 + (lane & 15);
                float v = acc[mi][ni][r];
                if (bias) v += bias[gn];
                if (EPI == 1) v += Rm[(long)gm * ldr + gn];
                if (EPI == 2) v = 0.5f * v * (1.0f + erff(v * 0.70710678118654752f));
                if (OUTBF) {
                    ((__hip_bfloat16*)Cout)[(long)gm * ldc + gn] = __float2bfloat16(v);
                } else {
                    ((float*)Cout)[(long)gm * ldc + gn] = v;
                    if (EPI == 1 && out2) out2[(long)gm * ldc + gn] = v;
                }
            }
        }
    }
}

// =====================================================================
// 128x128 tile MFMA GEMM — QKV projection; q,k,v all row-major out
// =====================================================================
__global__ __launch_bounds__(256) void gemm_qkv(
    const __hip_bfloat16* __restrict__ A, int lda, long sAlo,
    const __hip_bfloat16* __restrict__ Bt, int ldb, long sBhi,
    const float* __restrict__ bias, long sbhi,
    __hip_bfloat16* __restrict__ qb_, __hip_bfloat16* __restrict__ kb_,
    __hip_bfloat16* __restrict__ vb_,
    int M, int N, int K)
{
    __shared__ __hip_bfloat16 As[128 * 64];
    __shared__ __hip_bfloat16 Bs[128 * 64];

    const int zz = blockIdx.z;
    A  += zz * sAlo;
    Bt += zz * sBhi;
    bias += zz * sbhi;

    const int t = threadIdx.x;
    const int wid = t >> 6, lane = t & 63;
    const int wm = wid >> 1, wn = wid & 1;
    const int m0 = blockIdx.y * 128, n0 = blockIdx.x * 128;

    const int srow = t >> 3;
    const int scol = (t & 7) * 8;

    f32x4 acc[4][4] = {};

    for (int k0 = 0; k0 < K; k0 += 64) {
        #pragma unroll
        for (int i = 0; i < 4; ++i) {
            const __hip_bfloat16* ga = A + (long)(m0 + i * 32 + srow) * lda + k0 + scol;
            __hip_bfloat16* la = As + (i * 256 + wid * 64) * 8;
            gll16(ga, la);
            const __hip_bfloat16* gb = Bt + (long)(n0 + i * 32 + srow) * ldb + k0 + scol;
            __hip_bfloat16* lb = Bs + (i * 256 + wid * 64) * 8;
            gll16(gb, lb);
        }
        asm volatile("s_waitcnt vmcnt(0)" ::: "memory");
        __syncthreads();

        #pragma unroll
        for (int kk = 0; kk < 2; ++kk) {
            bf16x8 af[4], bfr[4];
            #pragma unroll
            for (int mi = 0; mi < 4; ++mi)
                af[mi] = *reinterpret_cast<const bf16x8*>(
                    &As[(wm * 64 + mi * 16 + (lane & 15)) * 64 + kk * 32 + (lane >> 4) * 8]);
            #pragma unroll
            for (int ni = 0; ni < 4; ++ni)
                bfr[ni] = *reinterpret_cast<const bf16x8*>(
                    &Bs[(wn * 64 + ni * 16 + (lane & 15)) * 64 + kk * 32 + (lane >> 4) * 8]);
            #pragma unroll
            for (int mi = 0; mi < 4; ++mi)
                #pragma unroll
                for (int ni = 0; ni < 4; ++ni)
                    acc[mi][ni] = __builtin_amdgcn_mfma_f32_16x16x32_bf16(
                        af[mi], bfr[ni], acc[mi][ni], 0, 0, 0);
        }
        __syncthreads();
    }

    #pragma unroll
    for (int mi = 0; mi < 4; ++mi) {
        #pragma unroll
        for (int r = 0; r < 4; ++r) {
            int gm = m0 + wm * 64 + mi * 16 + (lane >> 4) * 4 + r;
            if (gm >= M) continue;
            #pragma unroll
            for (int ni = 0; ni < 4; ++ni) {
                int gn = n0 + wn * 64 + ni * 16 + (lane & 15);
                if (gn >= N) continue;
                float v = acc[mi][ni][r] + bias[gn];
                int c = gn >> 6, e = gn & 63;
                __hip_bfloat16 bv = __float2bfloat16(v);
                __hip_bfloat16* dst = (c == 0) ? qb_ : (c == 1) ? kb_ : vb_;
                dst[(long)gm * DD + zz * 64 + e] = bv;
            }
        }
    }
}

// =====================================================================
// Fused flash attention: one block per (b,h). 4 waves x 256 threads.
// V read row-major and transposed during LDS staging.
// =====================================================================
__global__ __launch_bounds__(256) void attn_flash(
    const __hip_bfloat16* __restrict__ qbuf,
    const __hip_bfloat16* __restrict__ kbuf,
    const __hip_bfloat16* __restrict__ vbuf,  // [PADM][768] row-major
    __hip_bfloat16* __restrict__ ctx)         // [PADM][768]
{
    constexpr int KLD = 72;    // K lds row stride (elems)
    constexpr int VLD = 232;   // Vt lds row stride
    constexpr int PLD = 232;   // P lds row stride
    __shared__ __hip_bfloat16 Kl[208 * KLD];     // 29952 B
    __shared__ __hip_bfloat16 Vl[64 * VLD];      // 29696 B
    __shared__ __hip_bfloat16 Pl[4][16 * PLD];   // 29696 B

    const int h = blockIdx.x, b = blockIdx.y;
    const int t = threadIdx.x;
    const int w = t >> 6, lane = t & 63;
    const int l15 = lane & 15, g0 = lane >> 4;   // g0 in 0..3

    const long row0 = (long)b * 197;
    const int  hc   = h * 64;

    // ---- stage K: 208 rows x 8 groups of 8 elems
    for (int task = t; task < 208 * 8; task += 256) {
        int r = task >> 3, g = task & 7;
        float4 vv = *reinterpret_cast<const float4*>(kbuf + (row0 + r) * DD + hc + g * 8);
        *reinterpret_cast<float4*>(&Kl[r * KLD + g * 8]) = vv;
    }
    // ---- zero Vt cols [197,224)  (disjoint from transpose range below)
    const __hip_bfloat16 bz = __float2bfloat16(0.0f);
    for (int task = t; task < 64 * 27; task += 256) {
        int e = task / 27, c = 197 + (task - e * 27);
        Vl[e * VLD + c] = bz;
    }
    // ---- stage Vt transposed: vbuf rows (s) -> Vl[e][s]
    for (int task = t; task < 197 * 8; task += 256) {
        int r = task >> 3, g = task & 7;
        union { float4 f; __hip_bfloat16 hx[8]; } u;
        u.f = *reinterpret_cast<const float4*>(vbuf + (row0 + r) * DD + hc + g * 8);
        #pragma unroll
        for (int j = 0; j < 8; ++j)
            Vl[(g * 8 + j) * VLD + r] = u.hx[j];
    }
    __syncthreads();

    __hip_bfloat16* Pw = Pl[w];

    for (int qc = w; qc < 13; qc += 4) {
        const int q0 = qc * 16;

        const __hip_bfloat16* qsrc = qbuf + (row0 + q0 + l15) * DD + hc + g0 * 8;
        bf16x8 qf0 = *reinterpret_cast<const bf16x8*>(qsrc);
        bf16x8 qf1 = *reinterpret_cast<const bf16x8*>(qsrc + 32);

        // ---- QK^T: sacc[n] rows q=g0*4+r, cols k=n*16+l15
        f32x4 sacc[13];
        #pragma unroll
        for (int n = 0; n < 13; ++n) {
            bf16x8 kf0 = *reinterpret_cast<const bf16x8*>(&Kl[(n * 16 + l15) * KLD + g0 * 8]);
            bf16x8 kf1 = *reinterpret_cast<const bf16x8*>(&Kl[(n * 16 + l15) * KLD + 32 + g0 * 8]);
            f32x4 z = {0.f, 0.f, 0.f, 0.f};
            z = __builtin_amdgcn_mfma_f32_16x16x32_bf16(qf0, kf0, z, 0, 0, 0);
            sacc[n] = __builtin_amdgcn_mfma_f32_16x16x32_bf16(qf1, kf1, z, 0, 0, 0);
        }

        const int kcol = l15;   // k = n*16 + kcol
        float lrow[4];
        #pragma unroll
        for (int r = 0; r < 4; ++r) {
            float mx = -3.0e38f;
            #pragma unroll
            for (int n = 0; n < 13; ++n) {
                float s = sacc[n][r] * (1.0f / 4096.0f);
                if (n * 16 + kcol < 197) mx = fmaxf(mx, s);
            }
            #pragma unroll
            for (int off = 1; off < 16; off <<= 1) mx = fmaxf(mx, __shfl_xor(mx, off));
            float sum = 0.f;
            #pragma unroll
            for (int n = 0; n < 14; ++n) {
                float p = 0.f;
                if (n < 13 && n * 16 + kcol < 197) {
                    p = __expf(sacc[n][r] * (1.0f / 4096.0f) - mx);
                    sum += p;
                }
                Pw[(g0 * 4 + r) * PLD + n * 16 + kcol] = __float2bfloat16(p);
            }
            #pragma unroll
            for (int off = 1; off < 16; off <<= 1) sum += __shfl_xor(sum, off);
            lrow[r] = sum;
        }

        asm volatile("s_waitcnt lgkmcnt(0)" ::: "memory");

        // ---- PV: K-dim 224 (7 chunks of 32)
        f32x4 pv[4] = {};
        #pragma unroll
        for (int kc = 0; kc < 7; ++kc) {
            bf16x8 pf = *reinterpret_cast<const bf16x8*>(&Pw[l15 * PLD + kc * 32 + g0 * 8]);
            #pragma unroll
            for (int ni = 0; ni < 4; ++ni) {
                bf16x8 vf = *reinterpret_cast<const bf16x8*>(&Vl[(ni * 16 + l15) * VLD + kc * 32 + g0 * 8]);
                pv[ni] = __builtin_amdgcn_mfma_f32_16x16x32_bf16(pf, vf, pv[ni], 0, 0, 0);
            }
        }

        // ---- ctx = PV / l
        #pragma unroll
        for (int r = 0; r < 4; ++r) {
            int q = q0 + g0 * 4 + r;
            if (q >= 197) continue;
            float inv = 1.0f / lrow[r];
            #pragma unroll
            for (int ni = 0; ni < 4; ++ni)
                ctx[(row0 + q) * DD + hc + ni * 16 + l15] = __float2bfloat16(pv[ni][r] * inv);
        }
    }
}

// ---------------- LayerNorm: fp32 in, bf16 out ----------------
__global__ __launch_bounds__(256) void ln_kernel(
    const float* __restrict__ X, const float* __restrict__ g,
    const float* __restrict__ b, __hip_bfloat16* __restrict__ H)
{
    const long row = blockIdx.x;
    const float* x = X + row * DD;
    const int t = threadIdx.x;
    float v[3];
    float s = 0.f, s2 = 0.f;
    #pragma unroll
    for (int i = 0; i < 3; ++i) {
        v[i] = x[t + i * 256];
        s += v[i]; s2 += v[i] * v[i];
    }
    #pragma unroll
    for (int off = 1; off < 64; off <<= 1) {
        s  += __shfl_xor(s,  off);
        s2 += __shfl_xor(s2, off);
    }
    __shared__ float red[2][4];
    const int lane = t & 63, w = t >> 6;
    if (lane == 0) { red[0][w] = s; red[1][w] = s2; }
    __syncthreads();
    float S1 = red[0][0] + red[0][1] + red[0][2] + red[0][3];
    float S2 = red[1][0] + red[1][1] + red[1][2] + red[1][3];
    float mu  = S1 * (1.0f / 768.0f);
    float var = S2 * (1.0f / 768.0f) - mu * mu;
    float rs  = rsqrtf(var + 1e-5f);
    __hip_bfloat16* h = H + row * DD;
    #pragma unroll
    for (int i = 0; i < 3; ++i) {
        int c = t + i * 256;
        h[c] = __float2bfloat16((v[i] - mu) * rs * g[c] + b[c]);
    }
}

// ---------------- patchify: [B,C,H,W] f32 -> [B*196, 768] bf16 ----------------
__global__ void patchify_kernel(const float* __restrict__ img, __hip_bfloat16* __restrict__ patches)
{
    long idx = (long)blockIdx.x * 256 + threadIdx.x;
    const long total = (long)NB * NPAT * DD;
    if (idx >= total) return;
    int k  = (int)(idx % DD);
    long mp = idx / DD;
    int p  = (int)(mp % NPAT);
    long b = mp / NPAT;
    int c = k >> 8;
    int i = (k >> 4) & 15;
    int j = k & 15;
    int pr = p / 14, pc = p % 14;
    int hh = pr * 16 + i, ww = pc * 16 + j;
    patches[idx] = __float2bfloat16(img[((b * 3 + c) * 224 + hh) * 224 + ww]);
}

// ---------------- assemble x = concat(cls, tokens) + pos (fp32) ----------------
__global__ void assemble_kernel(const float* __restrict__ tok, const float* __restrict__ cls,
                                const float* __restrict__ pos, float* __restrict__ X)
{
    long idx = (long)blockIdx.x * 256 + threadIdx.x;
    if (idx >= NX) return;
    int d  = (int)(idx % DD);
    long bs = idx / DD;
    int s  = (int)(bs % SS);
    long b = bs / SS;
    float v = (s == 0) ? cls[d] : tok[(b * NPAT + s - 1) * DD + d];
    X[idx] = v + pos[(long)s * DD + d];
}

// ---------------- fp32 -> bf16 conversion (n multiple of 4) ----------------
__global__ void f2b_kernel(const float* __restrict__ src, __hip_bfloat16* __restrict__ dst, long n4)
{
    long i = (long)blockIdx.x * 256 + threadIdx.x;
    if (i >= n4) return;
    float4 v = *reinterpret_cast<const float4*>(&src[i * 4]);
    __hip_bfloat16 o[4] = { __float2bfloat16(v.x), __float2bfloat16(v.y),
                            __float2bfloat16(v.z), __float2bfloat16(v.w) };
    *reinterpret_cast<uint2*>(&dst[i * 4]) = *reinterpret_cast<const uint2*>(o);
}

// ---------------- fused 3-matrix fp32 -> bf16, 16 elems/thread ----------------
__global__ void f2b3_kernel(const float* __restrict__ s0, __hip_bfloat16* __restrict__ d0, long c0,
                            const float* __restrict__ s1, __hip_bfloat16* __restrict__ d1, long c1,
                            const float* __restrict__ s2, __hip_bfloat16* __restrict__ d2, long c2)
{
    long i = (long)blockIdx.x * 256 + threadIdx.x;   // chunk of 16 elems
    const float* s; __hip_bfloat16* d;
    if (i < c0)                { s = s0; d = d0; }
    else if (i < c0 + c1)      { s = s1; d = d1; i -= c0; }
    else if (i < c0 + c1 + c2) { s = s2; d = d2; i -= c0 + c1; }
    else return;
    #pragma unroll
    for (int u = 0; u < 4; ++u) {
        float4 v = *reinterpret_cast<const float4*>(&s[i * 16 + u * 4]);
        __hip_bfloat16 o[4] = { __float2bfloat16(v.x), __float2bfloat16(v.y),
                                __float2bfloat16(v.z), __float2bfloat16(v.w) };
        *reinterpret_cast<uint2*>(&d[i * 16 + u * 4]) = *reinterpret_cast<const uint2*>(o);
    }
}

// ---------------- pack per-head qkv weights ----------------
__global__ void qkvpack_kernel(const float* __restrict__ qw, const float* __restrict__ kw,
                               const float* __restrict__ vw, const float* __restrict__ qb,
                               const float* __restrict__ kb, const float* __restrict__ vb,
                               __hip_bfloat16* __restrict__ W, float* __restrict__ Bv)
{
    int idx = blockIdx.x * 256 + threadIdx.x;   // over 12*192*64
    if (idx >= NHH * 192 * 64) return;
    int d = idx & 63;
    int rest = idx >> 6;
    int j = rest % 192;
    int h = rest / 192;
    int c = j >> 6, e = j & 63;
    const float* src = (c == 0 ? qw : c == 1 ? kw : vw) + ((long)h * 64 + e) * 64 + d;
    W[((long)h * 256 + j) * 64 + d] = __float2bfloat16(*src);
    if (d == 0) {
        const float* sb = (c == 0 ? qb : c == 1 ? kb : vb) + h * 64 + e;
        Bv[h * 192 + j] = *sb;
    }
}

// ---------------- host ----------------
extern "C" void kernel_launch(void* const* d_in, const int* in_sizes, int n_in,
                              void* d_out, int out_size, void* d_ws, size_t ws_size,
                              hipStream_t stream)
{
    const float* images   = (const float*)d_in[0];
    const float* mapper_w = (const float*)d_in[1];
    const float* mapper_b = (const float*)d_in[2];
    const float* cls      = (const float*)d_in[3];
    const float* pos      = (const float*)d_in[4];
    const float* ln1_g    = (const float*)d_in[5];
    const float* ln1_b    = (const float*)d_in[6];
    const float* qw       = (const float*)d_in[7];
    const float* qb       = (const float*)d_in[8];
    const float* kw       = (const float*)d_in[9];
    const float* kb       = (const float*)d_in[10];
    const float* vw       = (const float*)d_in[11];
    const float* vb       = (const float*)d_in[12];
    const float* ow       = (const float*)d_in[13];
    const float* ob       = (const float*)d_in[14];
    const float* ln2_g    = (const float*)d_in[15];
    const float* ln2_b    = (const float*)d_in[16];
    const float* w1       = (const float*)d_in[17];
    const float* b1       = (const float*)d_in[18];
    const float* w2       = (const float*)d_in[19];
    const float* b2       = (const float*)d_in[20];
    float* out = (float*)d_out;

    // ---- workspace (bump allocator, 256B aligned)
    char* p0 = (char*)d_ws;
    char* pp = p0;
    auto alloc = [&](size_t bytes) { char* r = pp; pp += (bytes + 255) & ~(size_t)255; return r; };

    float*           x      = (float*)          alloc(NX * 4);
    __hip_bfloat16*  h16    = (__hip_bfloat16*) alloc((size_t)PADM2 * DD * 2);
    __hip_bfloat16*  ctx16  = (__hip_bfloat16*) alloc((size_t)PADM2 * DD * 2);
    __hip_bfloat16*  wbuf16 = (__hip_bfloat16*) alloc((size_t)(DD*DD + (size_t)FFF*DD*2) * 2);
    __hip_bfloat16*  wqkv16 = (__hip_bfloat16*) alloc((size_t)NHH * 256 * 64 * 2);
    float*           bqkv   = (float*)          alloc((size_t)NHH * 192 * 4);
    __hip_bfloat16*  qbuf   = (__hip_bfloat16*) alloc((size_t)PADM * DD * 2);
    __hip_bfloat16*  kbuf   = (__hip_bfloat16*) alloc((size_t)PADM * DD * 2);
    __hip_bfloat16*  vbuf   = (__hip_bfloat16*) alloc((size_t)PADM * DD * 2);
    // shared region: mid16 (78.6MB) | patches+tokens (57.9MB)
    char*            big    = alloc((size_t)PADM2 * FFF * 2);

    if ((size_t)(pp - p0) > ws_size) return;

    __hip_bfloat16* mid16     = (__hip_bfloat16*)big;
    __hip_bfloat16* patches16 = (__hip_bfloat16*)big;
    float*          tokens    = (float*)(big + (((size_t)NB * NPAT * DD * 2 + 255) & ~(size_t)255));

    __hip_bfloat16* ow16 = wbuf16;
    __hip_bfloat16* w116 = wbuf16 + (size_t)DD * DD;
    __hip_bfloat16* w216 = w116 + (size_t)FFF * DD;

    // ---- setup: patchify + mapper + assemble
    {
        long n = (long)NB * NPAT * DD;
        patchify_kernel<<<dim3((n + 255) / 256), dim3(256), 0, stream>>>(images, patches16);
        f2b_kernel<<<dim3((DD * DD / 4 + 255) / 256), dim3(256), 0, stream>>>(mapper_w, w116, DD * DD / 4);
        gemm128<0, false><<<dim3(DD / 128, (NB * NPAT) / 128), dim3(256), 0, stream>>>(
            patches16, DD, w116, DD, tokens, DD, mapper_b, nullptr, 0, nullptr,
            NB * NPAT, DD, DD);
        assemble_kernel<<<dim3((NX + 255) / 256), dim3(256), 0, stream>>>(tokens, cls, pos, x);
    }

    const int MT  = (TOK + 127) / 128;   // 99
    const int MT2 = (TOK + 255) / 256;   // 50
    const long C1 = (long)DD * DD / 16, C2 = (long)FFF * DD / 16;

    for (int l = 0; l < 12; ++l) {
        // ---- weight prep for this layer (fused, 16 elems/thread)
        f2b3_kernel<<<dim3((int)((C1 + 2 * C2 + 255) / 256)), dim3(256), 0, stream>>>(
            ow + (long)l * DD * DD, ow16, C1,
            w1 + (long)l * FFF * DD, w116, C2,
            w2 + (long)l * FFF * DD, w216, C2);
        qkvpack_kernel<<<dim3((NHH * 192 * 64 + 255) / 256), dim3(256), 0, stream>>>(
            qw + (long)l * NHH * DHH * DHH, kw + (long)l * NHH * DHH * DHH,
            vw + (long)l * NHH * DHH * DHH,
            qb + (long)l * DD, kb + (long)l * DD, vb + (long)l * DD,
            wqkv16, bqkv);

        // ---- LN1 -> h16
        ln_kernel<<<dim3(TOK), dim3(256), 0, stream>>>(x, ln1_g + l * DD, ln1_b + l * DD, h16);

        // ---- QKV (all row-major out); per-head A offset = 64 elems
        gemm_qkv<<<dim3(2, MT, NHH), dim3(256), 0, stream>>>(
            h16, DD, 64,
            wqkv16, 64, (long)256 * 64,
            bqkv, 192,
            qbuf, kbuf, vbuf,
            TOK, 192, 64);

        // ---- fused attention (scores+softmax+PV; V transposed in-kernel)
        attn_flash<<<dim3(NHH, NB), dim3(256), 0, stream>>>(qbuf, kbuf, vbuf, ctx16);

        // ---- x = x + ctx @ ow^T + ob
        gemm128<1, false><<<dim3(DD / 128, MT), dim3(256), 0, stream>>>(
            ctx16, DD, ow16, DD, x, DD, ob + l * DD, x, DD, nullptr,
            TOK, DD, DD);

        // ---- LN2 -> h16
        ln_kernel<<<dim3(TOK), dim3(256), 0, stream>>>(x, ln2_g + l * DD, ln2_b + l * DD, h16);

        // ---- mid = gelu(h @ w1^T + b1)  (256x128 tile, higher intensity)
        gemm256<2, true><<<dim3(FFF / 128, MT2), dim3(512), 0, stream>>>(
            h16, DD, w116, DD, mid16, FFF, b1 + l * FFF, nullptr, 0, nullptr,
            TOK, FFF, DD);

        // ---- x = x + mid @ w2^T + b2 (+ fused extraction)
        int slot = (l == 2) ? 0 : (l == 5) ? 1 : (l == 8) ? 2 : (l == 11) ? 3 : -1;
        float* o2 = (slot >= 0) ? out + (long)slot * NX : nullptr;
        gemm128<1, false><<<dim3(DD / 128, MT), dim3(256), 0, stream>>>(
            mid16, FFF, w216, FFF, x, DD, b2 + l * DD, x, DD, o2,
            TOK, DD, FFF);
    }
}

// Round 12
// 5246.818 us; speedup vs baseline: 2.3253x; 2.3253x over previous
//
#include <hip/hip_runtime.h>
#include <hip/hip_bf16.h>
#include <math.h>

// ---------------- problem constants ----------------
static constexpr int NB   = 64;           // batch
static constexpr int SS   = 197;          // tokens
static constexpr int DD   = 768;          // hidden
static constexpr int NHH  = 12;           // heads
static constexpr int DHH  = 64;           // head dim
static constexpr int FFF  = 3072;         // mlp hidden
static constexpr int TOK  = NB * SS;      // 12608
static constexpr int NPAT = 196;          // patches per image
static constexpr int PADM = 12672;        // TOK padded to multiple of 128
static constexpr int PADM2= 12800;        // TOK padded to multiple of 256
static constexpr long NX  = (long)TOK * DD;  // 9,682,944

typedef __attribute__((ext_vector_type(8))) short bf16x8;
typedef __attribute__((ext_vector_type(4))) float f32x4;

__device__ inline void gll16(const __hip_bfloat16* g, __hip_bfloat16* l) {
    __builtin_amdgcn_global_load_lds(
        (const __attribute__((address_space(1))) void*)g,
        (__attribute__((address_space(3))) void*)l, 16, 0, 0);
}

// =====================================================================
// 128x128 tile bf16 MFMA GEMM (3-buffer, stage-ahead-2, 1 barrier/iter)
// Used for mapper / proj / MLP2 (N=768).
// =====================================================================
template<int EPI, bool OUTBF>
__global__ __launch_bounds__(256, 4) void gemm128(
    const __hip_bfloat16* __restrict__ A, int lda,
    const __hip_bfloat16* __restrict__ Bt, int ldb,
    void* __restrict__ Cout, int ldc,
    const float* __restrict__ bias,
    const float* __restrict__ Rm, int ldr,
    float* __restrict__ out2,
    int M, int N, int K)
{
    __shared__ __hip_bfloat16 sh[3][2][128 * 32];   // 48 KiB

    const int nbx = gridDim.x;
    const int nwg = nbx * gridDim.y;
    int flat = blockIdx.y * nbx + blockIdx.x;
    {
        int q = nwg >> 3, r = nwg & 7;
        int xcd = flat & 7, idx = flat >> 3;
        flat = (xcd < r ? xcd * (q + 1) : r * (q + 1) + (xcd - r) * q) + idx;
    }
    const int m0 = (flat / nbx) * 128;
    const int n0 = (flat % nbx) * 128;

    const int t = threadIdx.x;
    const int wid = t >> 6, lane = t & 63;
    const int wm = wid >> 1, wn = wid & 1;
    const int l15 = lane & 15, g0 = lane >> 4;
    const int rcol = ((g0 ^ ((l15 >> 1) & 3)) * 8);

    const int srl = t >> 2, sg = t & 3;

    auto stage = [&](int buf, int k0) {
        #pragma unroll
        for (int j = 0; j < 2; ++j) {
            int row = j * 64 + srl;
            int gs = sg ^ ((row >> 1) & 3);
            gll16(A + (long)(m0 + row) * lda + k0 + gs * 8,
                  &sh[buf][0][row * 32 + sg * 8]);
        }
        #pragma unroll
        for (int j = 0; j < 2; ++j) {
            int row = j * 64 + srl;
            int gs = sg ^ ((row >> 1) & 3);
            gll16(Bt + (long)(n0 + row) * ldb + k0 + gs * 8,
                  &sh[buf][1][row * 32 + sg * 8]);
        }
    };

    f32x4 acc[4][4] = {};
    const int NT = K >> 5;

    stage(0, 0);
    stage(1, 32);
    asm volatile("s_waitcnt vmcnt(4)" ::: "memory");
    __builtin_amdgcn_sched_barrier(0);
    __builtin_amdgcn_s_barrier();
    __builtin_amdgcn_sched_barrier(0);

    int cur = 0;
    for (int kt = 0; kt < NT; ++kt) {
        const bool st2 = (kt + 2 < NT);
        const bool w1n = (kt + 1 < NT);
        int stbuf = cur + 2; if (stbuf >= 3) stbuf -= 3;

        bf16x8 af[4], bfr[4];
        #pragma unroll
        for (int mi = 0; mi < 4; ++mi)
            af[mi] = *reinterpret_cast<const bf16x8*>(
                &sh[cur][0][(wm * 64 + mi * 16 + l15) * 32 + rcol]);
        #pragma unroll
        for (int ni = 0; ni < 4; ++ni)
            bfr[ni] = *reinterpret_cast<const bf16x8*>(
                &sh[cur][1][(wn * 64 + ni * 16 + l15) * 32 + rcol]);

        if (st2) stage(stbuf, (kt + 2) << 5);

        asm volatile("s_waitcnt lgkmcnt(0)" ::: "memory");
        __builtin_amdgcn_sched_barrier(0);
        __builtin_amdgcn_s_setprio(1);
        #pragma unroll
        for (int mi = 0; mi < 4; ++mi)
            #pragma unroll
            for (int ni = 0; ni < 4; ++ni)
                acc[mi][ni] = __builtin_amdgcn_mfma_f32_16x16x32_bf16(
                    af[mi], bfr[ni], acc[mi][ni], 0, 0, 0);
        __builtin_amdgcn_s_setprio(0);
        __builtin_amdgcn_sched_barrier(0);
        if (st2)      { asm volatile("s_waitcnt vmcnt(4)" ::: "memory"); }
        else if (w1n) { asm volatile("s_waitcnt vmcnt(0)" ::: "memory"); }
        __builtin_amdgcn_sched_barrier(0);
        __builtin_amdgcn_s_barrier();
        __builtin_amdgcn_sched_barrier(0);

        cur = (cur == 2) ? 0 : cur + 1;
    }

    #pragma unroll
    for (int mi = 0; mi < 4; ++mi) {
        #pragma unroll
        for (int r = 0; r < 4; ++r) {
            int gm = m0 + wm * 64 + mi * 16 + (lane >> 4) * 4 + r;
            if (gm >= M) continue;
            #pragma unroll
            for (int ni = 0; ni < 4; ++ni) {
                int gn = n0 + wn * 64 + ni * 16 + (lane & 15);
                float v = acc[mi][ni][r];
                if (bias) v += bias[gn];
                if (EPI == 1) v += Rm[(long)gm * ldr + gn];
                if (EPI == 2) v = 0.5f * v * (1.0f + erff(v * 0.70710678118654752f));
                if (OUTBF) {
                    ((__hip_bfloat16*)Cout)[(long)gm * ldc + gn] = __float2bfloat16(v);
                } else {
                    ((float*)Cout)[(long)gm * ldc + gn] = v;
                    if (EPI == 1 && out2) out2[(long)gm * ldc + gn] = v;
                }
            }
        }
    }
}

// =====================================================================
// 256x128 tile bf16 MFMA GEMM, BK=32, 8 waves (4Mx2N, wave-tile 64x64),
// double-buffered LDS (48 KiB), stage-ahead-2, counted vmcnt(3),
// XOR bank-swizzle, setprio, XCD-swizzled grid.
// __launch_bounds__(512,4): reg cap 128/wave — VGPR(~56)+AGPR(64) fits
// (R11's (512,6) capped at ~85 and spilled acc to scratch: 733us).
// Used for MLP1 (N=3072).
// =====================================================================
template<int EPI, bool OUTBF>
__global__ __launch_bounds__(512, 4) void gemm256(
    const __hip_bfloat16* __restrict__ A, int lda,
    const __hip_bfloat16* __restrict__ Bt, int ldb,
    void* __restrict__ Cout, int ldc,
    const float* __restrict__ bias,
    const float* __restrict__ Rm, int ldr,
    float* __restrict__ out2,
    int M, int N, int K)
{
    __shared__ __hip_bfloat16 sh[2][(256 + 128) * 32];   // 48 KiB; A then B

    const int nbx = gridDim.x;
    const int nwg = nbx * gridDim.y;
    int flat = blockIdx.y * nbx + blockIdx.x;
    {
        int q = nwg >> 3, r = nwg & 7;
        int xcd = flat & 7, idx = flat >> 3;
        flat = (xcd < r ? xcd * (q + 1) : r * (q + 1) + (xcd - r) * q) + idx;
    }
    const int m0 = (flat / nbx) * 256;
    const int n0 = (flat % nbx) * 128;

    const int t = threadIdx.x;
    const int wid = t >> 6, lane = t & 63;
    const int wm = wid >> 1, wn = wid & 1;        // 4M x 2N
    const int l15 = lane & 15, g0 = lane >> 4;
    const int rcol = ((g0 ^ ((l15 >> 1) & 3)) * 8);

    const int srl = t >> 2, sg = t & 3;           // srl 0..127

    auto stage = [&](int buf, int k0) {
        #pragma unroll
        for (int j = 0; j < 2; ++j) {             // A: rows 0..255
            int row = j * 128 + srl;
            int gs = sg ^ ((row >> 1) & 3);
            gll16(A + (long)(m0 + row) * lda + k0 + gs * 8,
                  &sh[buf][row * 32 + sg * 8]);
        }
        {                                          // B: rows 0..127
            int gs = sg ^ ((srl >> 1) & 3);
            gll16(Bt + (long)(n0 + srl) * ldb + k0 + gs * 8,
                  &sh[buf][8192 + srl * 32 + sg * 8]);
        }
    };

    f32x4 acc[4][4] = {};
    const int NT = K >> 5;

    stage(0, 0);
    stage(1, 32);
    asm volatile("s_waitcnt vmcnt(3)" ::: "memory");
    __builtin_amdgcn_sched_barrier(0);
    __builtin_amdgcn_s_barrier();
    __builtin_amdgcn_sched_barrier(0);

    for (int kt = 0; kt < NT; ++kt) {
        const int cur = kt & 1;
        const bool st2 = (kt + 2 < NT);
        const bool w1n = (kt + 1 < NT);

        bf16x8 af[4], bfr[4];
        #pragma unroll
        for (int mi = 0; mi < 4; ++mi)
            af[mi] = *reinterpret_cast<const bf16x8*>(
                &sh[cur][(wm * 64 + mi * 16 + l15) * 32 + rcol]);
        #pragma unroll
        for (int ni = 0; ni < 4; ++ni)
            bfr[ni] = *reinterpret_cast<const bf16x8*>(
                &sh[cur][8192 + (wn * 64 + ni * 16 + l15) * 32 + rcol]);
        asm volatile("s_waitcnt lgkmcnt(0)" ::: "memory");
        __builtin_amdgcn_sched_barrier(0);
        __builtin_amdgcn_s_barrier();       // block-wide: buf[cur] fully read
        __builtin_amdgcn_sched_barrier(0);

        if (st2) stage(cur, (kt + 2) << 5);
        __builtin_amdgcn_s_setprio(1);
        #pragma unroll
        for (int mi = 0; mi < 4; ++mi)
            #pragma unroll
            for (int ni = 0; ni < 4; ++ni)
                acc[mi][ni] = __builtin_amdgcn_mfma_f32_16x16x32_bf16(
                    af[mi], bfr[ni], acc[mi][ni], 0, 0, 0);
        __builtin_amdgcn_s_setprio(0);
        __builtin_amdgcn_sched_barrier(0);
        if (st2)      { asm volatile("s_waitcnt vmcnt(3)" ::: "memory"); }  // kt+1 landed
        else if (w1n) { asm volatile("s_waitcnt vmcnt(0)" ::: "memory"); }  // tail drain
        __builtin_amdgcn_sched_barrier(0);
        __builtin_amdgcn_s_barrier();
        __builtin_amdgcn_sched_barrier(0);
    }

    #pragma unroll
    for (int mi = 0; mi < 4; ++mi) {
        #pragma unroll
        for (int r = 0; r < 4; ++r) {
            int gm = m0 + wm * 64 + mi * 16 + (lane >> 4) * 4 + r;
            if (gm >= M) continue;
            #pragma unroll
            for (int ni = 0; ni < 4; ++ni) {
                int gn = n0 + wn * 64 + ni * 16 + (lane & 15);
                float v = acc[mi][ni][r];
                if (bias) v += bias[gn];
                if (EPI == 1) v += Rm[(long)gm * ldr + gn];
                if (EPI == 2) v = 0.5f * v * (1.0f + erff(v * 0.70710678118654752f));
                if (OUTBF) {
                    ((__hip_bfloat16*)Cout)[(long)gm * ldc + gn] = __float2bfloat16(v);
                } else {
                    ((float*)Cout)[(long)gm * ldc + gn] = v;
                    if (EPI == 1 && out2) out2[(long)gm * ldc + gn] = v;
                }
            }
        }
    }
}

// =====================================================================
// 128x128 tile MFMA GEMM — QKV projection; q,k,v all row-major out
// =====================================================================
__global__ __launch_bounds__(256) void gemm_qkv(
    const __hip_bfloat16* __restrict__ A, int lda, long sAlo,
    const __hip_bfloat16* __restrict__ Bt, int ldb, long sBhi,
    const float* __restrict__ bias, long sbhi,
    __hip_bfloat16* __restrict__ qb_, __hip_bfloat16* __restrict__ kb_,
    __hip_bfloat16* __restrict__ vb_,
    int M, int N, int K)
{
    __shared__ __hip_bfloat16 As[128 * 64];
    __shared__ __hip_bfloat16 Bs[128 * 64];

    const int zz = blockIdx.z;
    A  += zz * sAlo;
    Bt += zz * sBhi;
    bias += zz * sbhi;

    const int t = threadIdx.x;
    const int wid = t >> 6, lane = t & 63;
    const int wm = wid >> 1, wn = wid & 1;
    const int m0 = blockIdx.y * 128, n0 = blockIdx.x * 128;

    const int srow = t >> 3;
    const int scol = (t & 7) * 8;

    f32x4 acc[4][4] = {};

    for (int k0 = 0; k0 < K; k0 += 64) {
        #pragma unroll
        for (int i = 0; i < 4; ++i) {
            const __hip_bfloat16* ga = A + (long)(m0 + i * 32 + srow) * lda + k0 + scol;
            __hip_bfloat16* la = As + (i * 256 + wid * 64) * 8;
            gll16(ga, la);
            const __hip_bfloat16* gb = Bt + (long)(n0 + i * 32 + srow) * ldb + k0 + scol;
            __hip_bfloat16* lb = Bs + (i * 256 + wid * 64) * 8;
            gll16(gb, lb);
        }
        asm volatile("s_waitcnt vmcnt(0)" ::: "memory");
        __syncthreads();

        #pragma unroll
        for (int kk = 0; kk < 2; ++kk) {
            bf16x8 af[4], bfr[4];
            #pragma unroll
            for (int mi = 0; mi < 4; ++mi)
                af[mi] = *reinterpret_cast<const bf16x8*>(
                    &As[(wm * 64 + mi * 16 + (lane & 15)) * 64 + kk * 32 + (lane >> 4) * 8]);
            #pragma unroll
            for (int ni = 0; ni < 4; ++ni)
                bfr[ni] = *reinterpret_cast<const bf16x8*>(
                    &Bs[(wn * 64 + ni * 16 + (lane & 15)) * 64 + kk * 32 + (lane >> 4) * 8]);
            #pragma unroll
            for (int mi = 0; mi < 4; ++mi)
                #pragma unroll
                for (int ni = 0; ni < 4; ++ni)
                    acc[mi][ni] = __builtin_amdgcn_mfma_f32_16x16x32_bf16(
                        af[mi], bfr[ni], acc[mi][ni], 0, 0, 0);
        }
        __syncthreads();
    }

    #pragma unroll
    for (int mi = 0; mi < 4; ++mi) {
        #pragma unroll
        for (int r = 0; r < 4; ++r) {
            int gm = m0 + wm * 64 + mi * 16 + (lane >> 4) * 4 + r;
            if (gm >= M) continue;
            #pragma unroll
            for (int ni = 0; ni < 4; ++ni) {
                int gn = n0 + wn * 64 + ni * 16 + (lane & 15);
                if (gn >= N) continue;
                float v = acc[mi][ni][r] + bias[gn];
                int c = gn >> 6, e = gn & 63;
                __hip_bfloat16 bv = __float2bfloat16(v);
                __hip_bfloat16* dst = (c == 0) ? qb_ : (c == 1) ? kb_ : vb_;
                dst[(long)gm * DD + zz * 64 + e] = bv;
            }
        }
    }
}

// =====================================================================
// Fused flash attention: one block per (b,h). 4 waves x 256 threads.
// V read row-major and transposed during LDS staging.
// =====================================================================
__global__ __launch_bounds__(256) void attn_flash(
    const __hip_bfloat16* __restrict__ qbuf,
    const __hip_bfloat16* __restrict__ kbuf,
    const __hip_bfloat16* __restrict__ vbuf,  // [PADM][768] row-major
    __hip_bfloat16* __restrict__ ctx)         // [PADM][768]
{
    constexpr int KLD = 72;    // K lds row stride (elems)
    constexpr int VLD = 232;   // Vt lds row stride
    constexpr int PLD = 232;   // P lds row stride
    __shared__ __hip_bfloat16 Kl[208 * KLD];     // 29952 B
    __shared__ __hip_bfloat16 Vl[64 * VLD];      // 29696 B
    __shared__ __hip_bfloat16 Pl[4][16 * PLD];   // 29696 B

    const int h = blockIdx.x, b = blockIdx.y;
    const int t = threadIdx.x;
    const int w = t >> 6, lane = t & 63;
    const int l15 = lane & 15, g0 = lane >> 4;   // g0 in 0..3

    const long row0 = (long)b * 197;
    const int  hc   = h * 64;

    // ---- stage K: 208 rows x 8 groups of 8 elems
    for (int task = t; task < 208 * 8; task += 256) {
        int r = task >> 3, g = task & 7;
        float4 vv = *reinterpret_cast<const float4*>(kbuf + (row0 + r) * DD + hc + g * 8);
        *reinterpret_cast<float4*>(&Kl[r * KLD + g * 8]) = vv;
    }
    // ---- zero Vt cols [197,224)
    const __hip_bfloat16 bz = __float2bfloat16(0.0f);
    for (int task = t; task < 64 * 27; task += 256) {
        int e = task / 27, c = 197 + (task - e * 27);
        Vl[e * VLD + c] = bz;
    }
    // ---- stage Vt transposed: vbuf rows (s) -> Vl[e][s]
    for (int task = t; task < 197 * 8; task += 256) {
        int r = task >> 3, g = task & 7;
        union { float4 f; __hip_bfloat16 hx[8]; } u;
        u.f = *reinterpret_cast<const float4*>(vbuf + (row0 + r) * DD + hc + g * 8);
        #pragma unroll
        for (int j = 0; j < 8; ++j)
            Vl[(g * 8 + j) * VLD + r] = u.hx[j];
    }
    __syncthreads();

    __hip_bfloat16* Pw = Pl[w];

    for (int qc = w; qc < 13; qc += 4) {
        const int q0 = qc * 16;

        const __hip_bfloat16* qsrc = qbuf + (row0 + q0 + l15) * DD + hc + g0 * 8;
        bf16x8 qf0 = *reinterpret_cast<const bf16x8*>(qsrc);
        bf16x8 qf1 = *reinterpret_cast<const bf16x8*>(qsrc + 32);

        // ---- QK^T: sacc[n] rows q=g0*4+r, cols k=n*16+l15
        f32x4 sacc[13];
        #pragma unroll
        for (int n = 0; n < 13; ++n) {
            bf16x8 kf0 = *reinterpret_cast<const bf16x8*>(&Kl[(n * 16 + l15) * KLD + g0 * 8]);
            bf16x8 kf1 = *reinterpret_cast<const bf16x8*>(&Kl[(n * 16 + l15) * KLD + 32 + g0 * 8]);
            f32x4 z = {0.f, 0.f, 0.f, 0.f};
            z = __builtin_amdgcn_mfma_f32_16x16x32_bf16(qf0, kf0, z, 0, 0, 0);
            sacc[n] = __builtin_amdgcn_mfma_f32_16x16x32_bf16(qf1, kf1, z, 0, 0, 0);
        }

        const int kcol = l15;   // k = n*16 + kcol
        float lrow[4];
        #pragma unroll
        for (int r = 0; r < 4; ++r) {
            float mx = -3.0e38f;
            #pragma unroll
            for (int n = 0; n < 13; ++n) {
                float s = sacc[n][r] * (1.0f / 4096.0f);
                if (n * 16 + kcol < 197) mx = fmaxf(mx, s);
            }
            #pragma unroll
            for (int off = 1; off < 16; off <<= 1) mx = fmaxf(mx, __shfl_xor(mx, off));
            float sum = 0.f;
            #pragma unroll
            for (int n = 0; n < 14; ++n) {
                float p = 0.f;
                if (n < 13 && n * 16 + kcol < 197) {
                    p = __expf(sacc[n][r] * (1.0f / 4096.0f) - mx);
                    sum += p;
                }
                Pw[(g0 * 4 + r) * PLD + n * 16 + kcol] = __float2bfloat16(p);
            }
            #pragma unroll
            for (int off = 1; off < 16; off <<= 1) sum += __shfl_xor(sum, off);
            lrow[r] = sum;
        }

        asm volatile("s_waitcnt lgkmcnt(0)" ::: "memory");

        // ---- PV: K-dim 224 (7 chunks of 32)
        f32x4 pv[4] = {};
        #pragma unroll
        for (int kc = 0; kc < 7; ++kc) {
            bf16x8 pf = *reinterpret_cast<const bf16x8*>(&Pw[l15 * PLD + kc * 32 + g0 * 8]);
            #pragma unroll
            for (int ni = 0; ni < 4; ++ni) {
                bf16x8 vf = *reinterpret_cast<const bf16x8*>(&Vl[(ni * 16 + l15) * VLD + kc * 32 + g0 * 8]);
                pv[ni] = __builtin_amdgcn_mfma_f32_16x16x32_bf16(pf, vf, pv[ni], 0, 0, 0);
            }
        }

        // ---- ctx = PV / l
        #pragma unroll
        for (int r = 0; r < 4; ++r) {
            int q = q0 + g0 * 4 + r;
            if (q >= 197) continue;
            float inv = 1.0f / lrow[r];
            #pragma unroll
            for (int ni = 0; ni < 4; ++ni)
                ctx[(row0 + q) * DD + hc + ni * 16 + l15] = __float2bfloat16(pv[ni][r] * inv);
        }
    }
}

// ---------------- LayerNorm: fp32 in, bf16 out ----------------
__global__ __launch_bounds__(256) void ln_kernel(
    const float* __restrict__ X, const float* __restrict__ g,
    const float* __restrict__ b, __hip_bfloat16* __restrict__ H)
{
    const long row = blockIdx.x;
    const float* x = X + row * DD;
    const int t = threadIdx.x;
    float v[3];
    float s = 0.f, s2 = 0.f;
    #pragma unroll
    for (int i = 0; i < 3; ++i) {
        v[i] = x[t + i * 256];
        s += v[i]; s2 += v[i] * v[i];
    }
    #pragma unroll
    for (int off = 1; off < 64; off <<= 1) {
        s  += __shfl_xor(s,  off);
        s2 += __shfl_xor(s2, off);
    }
    __shared__ float red[2][4];
    const int lane = t & 63, w = t >> 6;
    if (lane == 0) { red[0][w] = s; red[1][w] = s2; }
    __syncthreads();
    float S1 = red[0][0] + red[0][1] + red[0][2] + red[0][3];
    float S2 = red[1][0] + red[1][1] + red[1][2] + red[1][3];
    float mu  = S1 * (1.0f / 768.0f);
    float var = S2 * (1.0f / 768.0f) - mu * mu;
    float rs  = rsqrtf(var + 1e-5f);
    __hip_bfloat16* h = H + row * DD;
    #pragma unroll
    for (int i = 0; i < 3; ++i) {
        int c = t + i * 256;
        h[c] = __float2bfloat16((v[i] - mu) * rs * g[c] + b[c]);
    }
}

// ---------------- patchify: [B,C,H,W] f32 -> [B*196, 768] bf16 ----------------
__global__ void patchify_kernel(const float* __restrict__ img, __hip_bfloat16* __restrict__ patches)
{
    long idx = (long)blockIdx.x * 256 + threadIdx.x;
    const long total = (long)NB * NPAT * DD;
    if (idx >= total) return;
    int k  = (int)(idx % DD);
    long mp = idx / DD;
    int p  = (int)(mp % NPAT);
    long b = mp / NPAT;
    int c = k >> 8;
    int i = (k >> 4) & 15;
    int j = k & 15;
    int pr = p / 14, pc = p % 14;
    int hh = pr * 16 + i, ww = pc * 16 + j;
    patches[idx] = __float2bfloat16(img[((b * 3 + c) * 224 + hh) * 224 + ww]);
}

// ---------------- assemble x = concat(cls, tokens) + pos (fp32) ----------------
__global__ void assemble_kernel(const float* __restrict__ tok, const float* __restrict__ cls,
                                const float* __restrict__ pos, float* __restrict__ X)
{
    long idx = (long)blockIdx.x * 256 + threadIdx.x;
    if (idx >= NX) return;
    int d  = (int)(idx % DD);
    long bs = idx / DD;
    int s  = (int)(bs % SS);
    long b = bs / SS;
    float v = (s == 0) ? cls[d] : tok[(b * NPAT + s - 1) * DD + d];
    X[idx] = v + pos[(long)s * DD + d];
}

// ---------------- fp32 -> bf16 conversion (n multiple of 4) ----------------
__global__ void f2b_kernel(const float* __restrict__ src, __hip_bfloat16* __restrict__ dst, long n4)
{
    long i = (long)blockIdx.x * 256 + threadIdx.x;
    if (i >= n4) return;
    float4 v = *reinterpret_cast<const float4*>(&src[i * 4]);
    __hip_bfloat16 o[4] = { __float2bfloat16(v.x), __float2bfloat16(v.y),
                            __float2bfloat16(v.z), __float2bfloat16(v.w) };
    *reinterpret_cast<uint2*>(&dst[i * 4]) = *reinterpret_cast<const uint2*>(o);
}

// ---------------- fused 3-matrix fp32 -> bf16, 16 elems/thread ----------------
__global__ void f2b3_kernel(const float* __restrict__ s0, __hip_bfloat16* __restrict__ d0, long c0,
                            const float* __restrict__ s1, __hip_bfloat16* __restrict__ d1, long c1,
                            const float* __restrict__ s2, __hip_bfloat16* __restrict__ d2, long c2)
{
    long i = (long)blockIdx.x * 256 + threadIdx.x;   // chunk of 16 elems
    const float* s; __hip_bfloat16* d;
    if (i < c0)                { s = s0; d = d0; }
    else if (i < c0 + c1)      { s = s1; d = d1; i -= c0; }
    else if (i < c0 + c1 + c2) { s = s2; d = d2; i -= c0 + c1; }
    else return;
    #pragma unroll
    for (int u = 0; u < 4; ++u) {
        float4 v = *reinterpret_cast<const float4*>(&s[i * 16 + u * 4]);
        __hip_bfloat16 o[4] = { __float2bfloat16(v.x), __float2bfloat16(v.y),
                                __float2bfloat16(v.z), __float2bfloat16(v.w) };
        *reinterpret_cast<uint2*>(&d[i * 16 + u * 4]) = *reinterpret_cast<const uint2*>(o);
    }
}

// ---------------- pack per-head qkv weights ----------------
__global__ void qkvpack_kernel(const float* __restrict__ qw, const float* __restrict__ kw,
                               const float* __restrict__ vw, const float* __restrict__ qb,
                               const float* __restrict__ kb, const float* __restrict__ vb,
                               __hip_bfloat16* __restrict__ W, float* __restrict__ Bv)
{
    int idx = blockIdx.x * 256 + threadIdx.x;   // over 12*192*64
    if (idx >= NHH * 192 * 64) return;
    int d = idx & 63;
    int rest = idx >> 6;
    int j = rest % 192;
    int h = rest / 192;
    int c = j >> 6, e = j & 63;
    const float* src = (c == 0 ? qw : c == 1 ? kw : vw) + ((long)h * 64 + e) * 64 + d;
    W[((long)h * 256 + j) * 64 + d] = __float2bfloat16(*src);
    if (d == 0) {
        const float* sb = (c == 0 ? qb : c == 1 ? kb : vb) + h * 64 + e;
        Bv[h * 192 + j] = *sb;
    }
}

// ---------------- host ----------------
extern "C" void kernel_launch(void* const* d_in, const int* in_sizes, int n_in,
                              void* d_out, int out_size, void* d_ws, size_t ws_size,
                              hipStream_t stream)
{
    const float* images   = (const float*)d_in[0];
    const float* mapper_w = (const float*)d_in[1];
    const float* mapper_b = (const float*)d_in[2];
    const float* cls      = (const float*)d_in[3];
    const float* pos      = (const float*)d_in[4];
    const float* ln1_g    = (const float*)d_in[5];
    const float* ln1_b    = (const float*)d_in[6];
    const float* qw       = (const float*)d_in[7];
    const float* qb       = (const float*)d_in[8];
    const float* kw       = (const float*)d_in[9];
    const float* kb       = (const float*)d_in[10];
    const float* vw       = (const float*)d_in[11];
    const float* vb       = (const float*)d_in[12];
    const float* ow       = (const float*)d_in[13];
    const float* ob       = (const float*)d_in[14];
    const float* ln2_g    = (const float*)d_in[15];
    const float* ln2_b    = (const float*)d_in[16];
    const float* w1       = (const float*)d_in[17];
    const float* b1       = (const float*)d_in[18];
    const float* w2       = (const float*)d_in[19];
    const float* b2       = (const float*)d_in[20];
    float* out = (float*)d_out;

    // ---- workspace (bump allocator, 256B aligned)
    char* p0 = (char*)d_ws;
    char* pp = p0;
    auto alloc = [&](size_t bytes) { char* r = pp; pp += (bytes + 255) & ~(size_t)255; return r; };

    float*           x      = (float*)          alloc(NX * 4);
    __hip_bfloat16*  h16    = (__hip_bfloat16*) alloc((size_t)PADM2 * DD * 2);
    __hip_bfloat16*  ctx16  = (__hip_bfloat16*) alloc((size_t)PADM2 * DD * 2);
    __hip_bfloat16*  wbuf16 = (__hip_bfloat16*) alloc((size_t)(DD*DD + (size_t)FFF*DD*2) * 2);
    __hip_bfloat16*  wqkv16 = (__hip_bfloat16*) alloc((size_t)NHH * 256 * 64 * 2);
    float*           bqkv   = (float*)          alloc((size_t)NHH * 192 * 4);
    __hip_bfloat16*  qbuf   = (__hip_bfloat16*) alloc((size_t)PADM * DD * 2);
    __hip_bfloat16*  kbuf   = (__hip_bfloat16*) alloc((size_t)PADM * DD * 2);
    __hip_bfloat16*  vbuf   = (__hip_bfloat16*) alloc((size_t)PADM * DD * 2);
    // shared region: mid16 (78.6MB) | patches+tokens (57.9MB)
    char*            big    = alloc((size_t)PADM2 * FFF * 2);

    if ((size_t)(pp - p0) > ws_size) return;

    __hip_bfloat16* mid16     = (__hip_bfloat16*)big;
    __hip_bfloat16* patches16 = (__hip_bfloat16*)big;
    float*          tokens    = (float*)(big + (((size_t)NB * NPAT * DD * 2 + 255) & ~(size_t)255));

    __hip_bfloat16* ow16 = wbuf16;
    __hip_bfloat16* w116 = wbuf16 + (size_t)DD * DD;
    __hip_bfloat16* w216 = w116 + (size_t)FFF * DD;

    // ---- setup: patchify + mapper + assemble
    {
        long n = (long)NB * NPAT * DD;
        patchify_kernel<<<dim3((n + 255) / 256), dim3(256), 0, stream>>>(images, patches16);
        f2b_kernel<<<dim3((DD * DD / 4 + 255) / 256), dim3(256), 0, stream>>>(mapper_w, w116, DD * DD / 4);
        gemm128<0, false><<<dim3(DD / 128, (NB * NPAT) / 128), dim3(256), 0, stream>>>(
            patches16, DD, w116, DD, tokens, DD, mapper_b, nullptr, 0, nullptr,
            NB * NPAT, DD, DD);
        assemble_kernel<<<dim3((NX + 255) / 256), dim3(256), 0, stream>>>(tokens, cls, pos, x);
    }

    const int MT  = (TOK + 127) / 128;   // 99
    const int MT2 = (TOK + 255) / 256;   // 50
    const long C1 = (long)DD * DD / 16, C2 = (long)FFF * DD / 16;

    for (int l = 0; l < 12; ++l) {
        // ---- weight prep for this layer (fused, 16 elems/thread)
        f2b3_kernel<<<dim3((int)((C1 + 2 * C2 + 255) / 256)), dim3(256), 0, stream>>>(
            ow + (long)l * DD * DD, ow16, C1,
            w1 + (long)l * FFF * DD, w116, C2,
            w2 + (long)l * FFF * DD, w216, C2);
        qkvpack_kernel<<<dim3((NHH * 192 * 64 + 255) / 256), dim3(256), 0, stream>>>(
            qw + (long)l * NHH * DHH * DHH, kw + (long)l * NHH * DHH * DHH,
            vw + (long)l * NHH * DHH * DHH,
            qb + (long)l * DD, kb + (long)l * DD, vb + (long)l * DD,
            wqkv16, bqkv);

        // ---- LN1 -> h16
        ln_kernel<<<dim3(TOK), dim3(256), 0, stream>>>(x, ln1_g + l * DD, ln1_b + l * DD, h16);

        // ---- QKV (all row-major out); per-head A offset = 64 elems
        gemm_qkv<<<dim3(2, MT, NHH), dim3(256), 0, stream>>>(
            h16, DD, 64,
            wqkv16, 64, (long)256 * 64,
            bqkv, 192,
            qbuf, kbuf, vbuf,
            TOK, 192, 64);

        // ---- fused attention (scores+softmax+PV; V transposed in-kernel)
        attn_flash<<<dim3(NHH, NB), dim3(256), 0, stream>>>(qbuf, kbuf, vbuf, ctx16);

        // ---- x = x + ctx @ ow^T + ob
        gemm128<1, false><<<dim3(DD / 128, MT), dim3(256), 0, stream>>>(
            ctx16, DD, ow16, DD, x, DD, ob + l * DD, x, DD, nullptr,
            TOK, DD, DD);

        // ---- LN2 -> h16
        ln_kernel<<<dim3(TOK), dim3(256), 0, stream>>>(x, ln2_g + l * DD, ln2_b + l * DD, h16);

        // ---- mid = gelu(h @ w1^T + b1)  (256x128 tile, higher intensity)
        gemm256<2, true><<<dim3(FFF / 128, MT2), dim3(512), 0, stream>>>(
            h16, DD, w116, DD, mid16, FFF, b1 + l * FFF, nullptr, 0, nullptr,
            TOK, FFF, DD);

        // ---- x = x + mid @ w2^T + b2 (+ fused extraction)
        int slot = (l == 2) ? 0 : (l == 5) ? 1 : (l == 8) ? 2 : (l == 11) ? 3 : -1;
        float* o2 = (slot >= 0) ? out + (long)slot * NX : nullptr;
        gemm128<1, false><<<dim3(DD / 128, MT), dim3(256), 0, stream>>>(
            mid16, FFF, w216, FFF, x, DD, b2 + l * DD, x, DD, o2,
            TOK, DD, FFF);
    }
}